// Round 9
// baseline (616.028 us; speedup 1.0000x reference)
//
#include <hip/hip_runtime.h>

#define K_OFF   8
#define R_PAIRS 62500
#define NPAIRS  500000
#define N_IN    500000
#define N_OUT   125000
#define CIN     64
#define COUT    128
#define BN_EPS  1e-4f
#define SCAN_ELEMS 4096
#define NSB_OUT 31           // ceil(N_OUT / 4096)
#define OLD_TILES 8

typedef __bf16 bf16;
typedef __bf16 bf16x8 __attribute__((ext_vector_type(8)));
typedef float  f32x4  __attribute__((ext_vector_type(4)));
typedef unsigned int u32;

// z swizzle: inject column-group ^ row into bank bits 2-4 (f32-index space).
// Consistent for writes (col = slice-owned) and GEMM reads (col = ks*32+kr0).
__device__ __forceinline__ int zoff(int row, int col) {
    int idx = (row << 9) + col;
    return idx ^ ((((col >> 5) ^ row) & 7) << 2);
}

// ==================== BN statistics ====================
template<int C>
__global__ void bn_stats_kernel(const float* __restrict__ x, int n_rows,
                                float* __restrict__ sums /* [2C] */) {
    constexpr int CG = C / 4;
    int tid = blockIdx.x * blockDim.x + threadIdx.x;
    int nth = gridDim.x * blockDim.x;
    const float4* x4 = (const float4*)x;
    long n4 = (long)n_rows * CG;
    int cg = tid % CG;
    float s[4] = {0,0,0,0}, q[4] = {0,0,0,0};
    for (long i = tid; i < n4; i += nth) {
        float4 v = x4[i];
        float f[4] = {v.x, v.y, v.z, v.w};
        #pragma unroll
        for (int j = 0; j < 4; j++) { s[j] += f[j]; q[j] += f[j] * f[j]; }
    }
    __shared__ float acc[2 * C];
    for (int i = threadIdx.x; i < 2 * C; i += blockDim.x) acc[i] = 0.f;
    __syncthreads();
    #pragma unroll
    for (int j = 0; j < 4; j++) {
        atomicAdd(&acc[cg * 4 + j], s[j]);
        atomicAdd(&acc[C + cg * 4 + j], q[j]);
    }
    __syncthreads();
    for (int i = threadIdx.x; i < 2 * C; i += blockDim.x) atomicAdd(&sums[i], acc[i]);
}

template<int C>
__global__ void bn_finalize_kernel(const float* __restrict__ sums,
                                   const float* __restrict__ gamma,
                                   const float* __restrict__ beta,
                                   float inv_n, float* __restrict__ ss) {
    int c = threadIdx.x;
    if (c < C) {
        float m  = sums[c] * inv_n;
        float v  = sums[C + c] * inv_n - m * m;
        float sc = gamma[c] * rsqrtf(v + BN_EPS);
        ss[c]     = sc;
        ss[C + c] = beta[c] - m * sc;
    }
}

// BN2 finalize from 64 striped partial-sum copies
__global__ void bn_finalize2_kernel(const float* __restrict__ S /*[64][256]*/,
                                    const float* __restrict__ gamma,
                                    const float* __restrict__ beta,
                                    float* __restrict__ ss) {
    int c = threadIdx.x;   // 128
    float s = 0.f, q = 0.f;
    for (int st = 0; st < 64; st++) { s += S[st * 256 + c]; q += S[st * 256 + 128 + c]; }
    float m = s / (float)N_OUT;
    float v = q / (float)N_OUT - m * m;
    float sc = gamma[c] * rsqrtf(v + BN_EPS);
    ss[c] = sc; ss[128 + c] = beta[c] - m * sc;
}

// ==================== BN apply + ReLU -> bf16 (fp32 in) ====================
template<int C>
__global__ void bn_apply_f32_kernel(const float* __restrict__ x, const float* __restrict__ ss,
                                    bf16* __restrict__ xo, long items /* rows*C/8 */) {
    constexpr int CG = C / 8;
    long i = (long)blockIdx.x * blockDim.x + threadIdx.x;
    long stride = (long)gridDim.x * blockDim.x;   // multiple of CG
    int cg = (int)(i % CG);
    float sc[8], sh[8];
    #pragma unroll
    for (int j = 0; j < 8; j++) { sc[j] = ss[cg*8+j]; sh[j] = ss[C + cg*8+j]; }
    for (; i < items; i += stride) {
        const float4* p = (const float4*)(x + i * 8);
        float4 a = p[0], b = p[1];
        float f[8] = {a.x,a.y,a.z,a.w,b.x,b.y,b.z,b.w};
        bf16x8 h;
        #pragma unroll
        for (int j = 0; j < 8; j++) h[j] = (bf16)fmaxf(f[j]*sc[j] + sh[j], 0.f);
        *(bf16x8*)(xo + i * 8) = h;
    }
}

// ==================== weight prepack (fragment order) ====================
__global__ void pack12_kernel(const float* __restrict__ W1, const float* __restrict__ W2,
                              bf16* __restrict__ Wf) {
    int idx = blockIdx.x * 256 + threadIdx.x;      // 131072
    int j = idx & 7;
    int lane = (idx >> 3) & 63;
    int fi = idx >> 9;            // 0..255
    int ks = fi >> 4, nfrag = fi & 15;
    int k512 = ks * 32 + (lane >> 4) * 8 + j;
    int koff = k512 >> 6, kc = k512 & 63;
    int c = nfrag * 16 + (lane & 15);
    const float* W = (c < 128) ? W1 : W2;
    Wf[idx] = (bf16)W[((long)koff * CIN + kc) * COUT + (c & 127)];
}

__global__ void packS_kernel(const float* __restrict__ Ws, bf16* __restrict__ Wf) {
    int idx = blockIdx.x * 256 + threadIdx.x;      // 131072
    int j = idx & 7;
    int lane = (idx >> 3) & 63;
    int fi = idx >> 9;            // 0..255
    int ksg = fi >> 3, nfrag = fi & 7;
    int k1024 = ksg * 32 + (lane >> 4) * 8 + j;
    int koff = k1024 >> 7, kc = k1024 & 127;
    int c = nfrag * 16 + (lane & 15);
    Wf[idx] = (bf16)Ws[((long)koff * COUT + kc) * COUT + c];
}

// ==================== hist over out ====================
__global__ void histO_kernel(const int* __restrict__ oidx, u32* __restrict__ countO) {
    int p = blockIdx.x * blockDim.x + threadIdx.x;
    int stride = gridDim.x * blockDim.x;
    for (; p < NPAIRS; p += stride) atomicAdd(&countO[oidx[p]], 1u);
}

// ==================== 3-level scan ====================
__global__ void scan1_kernel(const u32* __restrict__ counts, u32* __restrict__ bsum, int n) {
    __shared__ u32 sd[256];
    int tid = threadIdx.x;
    int base = blockIdx.x * SCAN_ELEMS + tid * 16;
    u32 s = 0;
    #pragma unroll
    for (int j = 0; j < 16; j++) { int i = base + j; if (i < n) s += counts[i]; }
    sd[tid] = s; __syncthreads();
    for (int st = 128; st > 0; st >>= 1) { if (tid < st) sd[tid] += sd[tid + st]; __syncthreads(); }
    if (tid == 0) bsum[blockIdx.x] = sd[0];
}

__global__ void scan2_kernel(u32* __restrict__ bsum, u32* __restrict__ starts, int nb, int n) {
    __shared__ u32 sd[256];
    int tid = threadIdx.x;
    u32 v = (tid < nb) ? bsum[tid] : 0;
    sd[tid] = v; __syncthreads();
    for (int st = 1; st < 256; st <<= 1) {
        u32 t = (tid >= st) ? sd[tid - st] : 0;
        __syncthreads();
        sd[tid] += t;
        __syncthreads();
    }
    if (tid < nb) bsum[tid] = sd[tid] - v;     // exclusive
    if (tid == 255) starts[n] = sd[255];       // total
}

__global__ void scan3_kernel(const u32* __restrict__ counts, const u32* __restrict__ bsum,
                             u32* __restrict__ starts, int n) {
    __shared__ u32 sd[256];
    int tid = threadIdx.x;
    int base = blockIdx.x * SCAN_ELEMS + tid * 16;
    u32 v[16]; u32 s = 0;
    #pragma unroll
    for (int j = 0; j < 16; j++) { int i = base + j; v[j] = (i < n) ? counts[i] : 0; s += v[j]; }
    sd[tid] = s; __syncthreads();
    for (int st = 1; st < 256; st <<= 1) {
        u32 t = (tid >= st) ? sd[tid - st] : 0;
        __syncthreads();
        sd[tid] += t;
        __syncthreads();
    }
    u32 run = bsum[blockIdx.x] + sd[tid] - s;
    #pragma unroll
    for (int j = 0; j < 16; j++) { int i = base + j; if (i < n) starts[i] = run; run += v[j]; }
}

// ==================== build fused list: in(20b) | rowLocal(4b)<<20 | k(3b)<<24 ====
__global__ void buildF_kernel(const int* __restrict__ iidx, const int* __restrict__ oidx,
                              const u32* __restrict__ rowstart, u32* __restrict__ cursorO,
                              u32* __restrict__ listF) {
    int p = blockIdx.x * 256 + threadIdx.x;
    if (p >= NPAIRS) return;
    int o = oidx[p];
    int k = p / R_PAIRS;
    u32 np = rowstart[o] + atomicAdd(&cursorO[o], 1u);
    listF[np] = (u32)iidx[p] | ((u32)(o & 15) << 20) | ((u32)k << 24);
}

// ==================== fused conv1+conv2: staged gather + owner reduce ============
// block: 16 out rows. Tile loop: stage 64 entries (x1 rows, bf16) into As (swizzled),
// then owner-reduce: thread (row=tid>>4, sl=tid&15) owns k=sl>>1, ch 32-slice (sl&1).
// z [16][512] fp32 via zoff. GEMM waves: wave w -> cat cols w*64..+64.
__global__ __launch_bounds__(256) void fused12_kernel(
    const bf16* __restrict__ x1, const bf16* __restrict__ Wf,
    const u32* __restrict__ rowstart, const u32* __restrict__ listF,
    bf16* __restrict__ y1, bf16* __restrict__ y2b, float* __restrict__ sums2s)
{
    __shared__ float z[16 * 512];     // 32 KB
    __shared__ bf16 As[64 * 64];      // 8 KB staged entry rows
    u32* s_meta = (u32*)&z[16 * 512 - 64];   // alias z tail (dead until z-write)

    int tid = threadIdx.x, lane = tid & 63, wave = tid >> 6;
    int o0 = blockIdx.x * 16;
    int nrow = min(16, N_OUT - o0);
    u32 lo = rowstart[o0], hi = rowstart[o0 + nrow];
    u32 span = hi - lo;

    int myrow = tid >> 4, sl = tid & 15;
    int kown = sl >> 1, ch0 = (sl & 1) * 32;

    f32x4 a[8];
    #pragma unroll
    for (int g = 0; g < 8; g++) a[g] = (f32x4)(0.f);

    for (u32 t0 = 0; t0 < span; t0 += 64) {
        int ne = (int)min(64u, span - t0);
        __syncthreads();          // previous reduce done reading As/meta
        {
            int e = tid >> 2, q = tid & 3;
            if (e < ne) {
                u32 w = listF[lo + t0 + e];
                if (q == 0) s_meta[e] = ((w >> 20) & 15) | ((w >> 24) << 4);
                int in = w & 0xFFFFF;
                const int4* src = (const int4*)((const char*)x1 + (size_t)in * 128 + q * 32);
                int4 v0 = src[0], v1 = src[1];
                char* db = (char*)As;
                *(int4*)(db + ((e * 128 + q * 32)      ^ ((e & 7) << 4))) = v0;
                *(int4*)(db + ((e * 128 + q * 32 + 16) ^ ((e & 7) << 4))) = v1;
            }
        }
        __syncthreads();
        // owner reduce from LDS
        for (int e = 0; e < ne; e++) {
            u32 m = s_meta[e];
            if ((int)(m & 15) != myrow || (int)(m >> 4) != kown) continue;
            const char* sb = (const char*)As;
            #pragma unroll
            for (int u = 0; u < 4; u++) {
                int bo = (e * 128 + ch0 * 2 + u * 16) ^ ((e & 7) << 4);
                int4 vi = *(const int4*)(sb + bo);
                bf16x8 hv = *(bf16x8*)&vi;
                #pragma unroll
                for (int j = 0; j < 8; j++)
                    a[u * 2 + (j >> 2)][j & 3] += (float)hv[j];
            }
        }
    }
    __syncthreads();   // reduce done; z (incl. meta alias) can be written

    // z write (full coverage by owners)
    {
        int colb = kown * 64 + ch0;
        #pragma unroll
        for (int g = 0; g < 8; g++)
            *(f32x4*)&z[zoff(myrow, colb + g * 4)] = a[g];
    }
    __syncthreads();

    // ---- GEMM: [16 x 512] x [512 x 256] ----
    int l15 = lane & 15, kr0 = (lane >> 4) * 8;
    f32x4 acc[4];
    #pragma unroll
    for (int nf = 0; nf < 4; nf++) acc[nf] = (f32x4)(0.f);
    for (int ks = 0; ks < 16; ks++) {
        int colb = ks * 32 + kr0;
        f32x4 a0 = *(f32x4*)&z[zoff(l15, colb)];
        f32x4 a1 = *(f32x4*)&z[zoff(l15, colb + 4)];
        bf16x8 af;
        #pragma unroll
        for (int j = 0; j < 4; j++) { af[j] = (bf16)a0[j]; af[4 + j] = (bf16)a1[j]; }
        #pragma unroll
        for (int nf = 0; nf < 4; nf++) {
            bf16x8 bf = *(const bf16x8*)(Wf + ((size_t)(ks * 16 + wave * 4 + nf) * 64 + lane) * 8);
            acc[nf] = __builtin_amdgcn_mfma_f32_16x16x32_bf16(af, bf, acc[nf], 0, 0, 0);
        }
    }
    __syncthreads();   // all z reads done -> reuse as stage

    // stage bf16 [16 rows][256 cat cols]
    bf16* st = (bf16*)z;
    int rb = (lane >> 4) * 4;
    #pragma unroll
    for (int nf = 0; nf < 4; nf++)
        #pragma unroll
        for (int j = 0; j < 4; j++)
            st[(rb + j) * 256 + wave * 64 + nf * 16 + l15] = (bf16)acc[nf][j];
    __syncthreads();

    // BN2 stats over y1 cols (0..127), striped atomics
    if (tid < 128) {
        float s = 0.f, q = 0.f;
        for (int r = 0; r < nrow; r++) { float v = (float)st[r * 256 + tid]; s += v; q += v * v; }
        int sb = (blockIdx.x & 63) * 256;
        atomicAdd(&sums2s[sb + tid], s);
        atomicAdd(&sums2s[sb + 128 + tid], q);
    }
    // output: thread -> (row, 32B segment)
    {
        int row = tid >> 4, seg = tid & 15;
        if (row < nrow) {
            const int4* src = (const int4*)(st + row * 256 + seg * 16);
            int4 v0 = src[0], v1 = src[1];
            bf16* dst = (seg < 8) ? (y1  + (size_t)(o0 + row) * 128 + seg * 16)
                                  : (y2b + (size_t)(o0 + row) * 128 + (seg - 8) * 16);
            ((int4*)dst)[0] = v0; ((int4*)dst)[1] = v1;
        }
    }
}

// ==================== fused submanifold conv: staged gather + owner reduce ========
// Thread (row, sl): ch slice (sl&3)*32, k in {sl>>2, 4+(sl>>2)} (two halves, static acc).
// BN2+ReLU applied in the fp32 reduce. Two K=512 GEMM halves share z.
__global__ __launch_bounds__(256) void fusedS_kernel(
    const bf16* __restrict__ y1, const bf16* __restrict__ Wf, const float* __restrict__ ss2,
    const u32* __restrict__ rowstart, const u32* __restrict__ listF,
    const bf16* __restrict__ y2b, float* __restrict__ out)
{
    __shared__ float z[16 * 512];     // 32 KB
    __shared__ bf16 As[64 * 128];     // 16 KB staged entry rows
    __shared__ float s_sc[128], s_sh[128];
    u32* s_meta = (u32*)&z[16 * 512 - 64];

    int tid = threadIdx.x, lane = tid & 63, wave = tid >> 6;
    if (tid < 128) { s_sc[tid] = ss2[tid]; s_sh[tid] = ss2[128 + tid]; }
    int o0 = blockIdx.x * 16;
    int nrow = min(16, N_OUT - o0);
    u32 lo = rowstart[o0], hi = rowstart[o0 + nrow];
    u32 span = hi - lo;

    int myrow = tid >> 4, sl = tid & 15;
    int kq = sl >> 2, ch0 = (sl & 3) * 32;

    f32x4 aA[8], aB[8];
    #pragma unroll
    for (int g = 0; g < 8; g++) { aA[g] = (f32x4)(0.f); aB[g] = (f32x4)(0.f); }

    for (u32 t0 = 0; t0 < span; t0 += 64) {
        int ne = (int)min(64u, span - t0);
        __syncthreads();          // prev reduce done (and s_sc ready on first iter)
        {
            int e = tid >> 2, q = tid & 3;
            if (e < ne) {
                u32 w = listF[lo + t0 + e];
                if (q == 0) s_meta[e] = ((w >> 20) & 15) | ((w >> 24) << 4);
                int in = w & 0xFFFFF;
                const int4* src = (const int4*)((const char*)y1 + (size_t)in * 256 + q * 64);
                int4 v0 = src[0], v1 = src[1], v2 = src[2], v3 = src[3];
                char* db = (char*)As;
                int b = (e * 256 + q * 64) ^ ((e & 7) << 4);
                *(int4*)(db + b) = v0;
                *(int4*)(db + (b ^ 16)) = v1;     // +16 within swizzle-invariant bits? no:
                // careful: compute each offset independently
                *(int4*)(db + ((e * 256 + q * 64 + 16) ^ ((e & 7) << 4))) = v1;
                *(int4*)(db + ((e * 256 + q * 64 + 32) ^ ((e & 7) << 4))) = v2;
                *(int4*)(db + ((e * 256 + q * 64 + 48) ^ ((e & 7) << 4))) = v3;
            }
        }
        __syncthreads();
        for (int e = 0; e < ne; e++) {
            u32 m = s_meta[e];
            if ((int)(m & 15) != myrow) continue;
            int k = (int)(m >> 4);
            if ((k & 3) != kq) continue;
            const char* sb = (const char*)As;
            f32x4 t[8];
            #pragma unroll
            for (int u = 0; u < 4; u++) {
                int bo = (e * 256 + ch0 * 2 + u * 16) ^ ((e & 7) << 4);
                int4 vi = *(const int4*)(sb + bo);
                bf16x8 hv = *(bf16x8*)&vi;
                #pragma unroll
                for (int j = 0; j < 8; j++) {
                    int c = ch0 + u * 8 + j;
                    t[u * 2 + (j >> 2)][j & 3] = fmaxf((float)hv[j] * s_sc[c] + s_sh[c], 0.f);
                }
            }
            if (k < 4) {
                #pragma unroll
                for (int g = 0; g < 8; g++) aA[g] += t[g];
            } else {
                #pragma unroll
                for (int g = 0; g < 8; g++) aB[g] += t[g];
            }
        }
    }

    int l15 = lane & 15, kr0 = (lane >> 4) * 8;
    f32x4 acc[2];
    acc[0] = (f32x4)(0.f); acc[1] = (f32x4)(0.f);
    int colw = kq * 128 + ch0;

    #pragma unroll
    for (int h = 0; h < 2; h++) {
        __syncthreads();   // h=0: reduce done; h=1: GEMM h=0 z reads done
        if (h == 0) {
            #pragma unroll
            for (int g = 0; g < 8; g++) *(f32x4*)&z[zoff(myrow, colw + g * 4)] = aA[g];
        } else {
            #pragma unroll
            for (int g = 0; g < 8; g++) *(f32x4*)&z[zoff(myrow, colw + g * 4)] = aB[g];
        }
        __syncthreads();

        for (int ks = 0; ks < 16; ks++) {
            int colb = ks * 32 + kr0;
            f32x4 a0 = *(f32x4*)&z[zoff(l15, colb)];
            f32x4 a1 = *(f32x4*)&z[zoff(l15, colb + 4)];
            bf16x8 af;
            #pragma unroll
            for (int j = 0; j < 4; j++) { af[j] = (bf16)a0[j]; af[4 + j] = (bf16)a1[j]; }
            #pragma unroll
            for (int nf = 0; nf < 2; nf++) {
                int fi = (h * 16 + ks) * 8 + wave * 2 + nf;
                bf16x8 bf = *(const bf16x8*)(Wf + ((size_t)fi * 64 + lane) * 8);
                acc[nf] = __builtin_amdgcn_mfma_f32_16x16x32_bf16(af, bf, acc[nf], 0, 0, 0);
            }
        }
    }
    __syncthreads();

    // stage fp32 [16][128]
    int rb = (lane >> 4) * 4;
    #pragma unroll
    for (int nf = 0; nf < 2; nf++)
        #pragma unroll
        for (int j = 0; j < 4; j++)
            z[(rb + j) * 128 + wave * 32 + nf * 16 + l15] = acc[nf][j];
    __syncthreads();

    {
        int orow = tid >> 4, seg = tid & 15;   // 8 floats each
        if (orow < nrow) {
            f32x4 s0 = *(f32x4*)&z[orow * 128 + seg * 8];
            f32x4 s1 = *(f32x4*)&z[orow * 128 + seg * 8 + 4];
            int4 yv = *(const int4*)(y2b + (size_t)(o0 + orow) * 128 + seg * 8);
            bf16x8 hy = *(bf16x8*)&yv;
            float4 w0 = make_float4(s0[0] + (float)hy[0], s0[1] + (float)hy[1],
                                    s0[2] + (float)hy[2], s0[3] + (float)hy[3]);
            float4 w1 = make_float4(s1[0] + (float)hy[4], s1[1] + (float)hy[5],
                                    s1[2] + (float)hy[6], s1[3] + (float)hy[7]);
            float* dst = out + (size_t)(o0 + orow) * 128 + seg * 8;
            *(float4*)dst = w0;
            *(float4*)(dst + 4) = w1;
        }
    }
}

// ==================== fallback (round-1 atomic path) ====================
__global__ __launch_bounds__(256) void conv12_atomic_kernel(
    const float* __restrict__ x,
    const float* __restrict__ W1, const float* __restrict__ W2,
    const int* __restrict__ in_idx, const int* __restrict__ out_idx,
    const float* __restrict__ ss1,
    float* __restrict__ y1, float* __restrict__ y2)
{
    int k    = blockIdx.y;
    int tid  = threadIdx.x;
    int wave = tid >> 6, lane = tid & 63;

    __shared__ bf16 As[64 * 64];
    __shared__ int  s_out[64];
    __shared__ float s_sc[64], s_sh[64];
    char* asb = (char*)As;

    if (tid < 64) { s_sc[tid] = ss1[tid]; s_sh[tid] = ss1[64 + tid]; }

    const float* Wk = ((wave & 2) ? W2 : W1) + (long)k * CIN * COUT;
    int nbase = (wave & 1) * 64;
    int l15 = lane & 15;
    int kr0 = (lane >> 4) * 8;

    bf16x8 bfrag[2][4];
    #pragma unroll
    for (int ks = 0; ks < 2; ks++)
        #pragma unroll
        for (int nf = 0; nf < 4; nf++) {
            const float* p = Wk + (long)(ks * 32 + kr0) * COUT + nbase + nf * 16 + l15;
            bf16x8 b;
            #pragma unroll
            for (int j = 0; j < 8; j++) b[j] = (bf16)p[(long)j * COUT];
            bfrag[ks][nf] = b;
        }

    const int* in_k  = in_idx  + k * R_PAIRS;
    const int* out_k = out_idx + k * R_PAIRS;
    float* ybase = (wave & 2) ? y2 : y1;

    int grow = tid >> 2;
    int gcol = (tid & 3) * 16;

    __syncthreads();

    for (int t = 0; t < OLD_TILES; t++) {
        int pair0 = blockIdx.x * (OLD_TILES * 64) + t * 64;
        {
            int p = pair0 + grow;
            bool valid = p < R_PAIRS;
            long src = valid ? (long)in_k[p] : 0;
            const float4* xr = (const float4*)(x + src * CIN + gcol);
            #pragma unroll
            for (int g = 0; g < 2; g++) {
                float4 va = make_float4(0, 0, 0, 0), vb = va;
                if (valid) { va = xr[g * 2]; vb = xr[g * 2 + 1]; }
                float f[8] = {va.x, va.y, va.z, va.w, vb.x, vb.y, vb.z, vb.w};
                bf16x8 h;
                #pragma unroll
                for (int j = 0; j < 8; j++) {
                    int c = gcol + g * 8 + j;
                    h[j] = (bf16)fmaxf(f[j] * s_sc[c] + s_sh[c], 0.f);
                }
                int boff = ((grow * 128) + (gcol + g * 8) * 2) ^ ((grow & 7) << 4);
                *(bf16x8*)(asb + boff) = h;
            }
        }
        if (tid < 64) {
            int p = pair0 + tid;
            s_out[tid] = (p < R_PAIRS) ? out_k[p] : -1;
        }
        __syncthreads();

        f32x4 acc[4][4];
        #pragma unroll
        for (int m = 0; m < 4; m++)
            #pragma unroll
            for (int n = 0; n < 4; n++) acc[m][n] = (f32x4)(0.f);

        #pragma unroll
        for (int ks = 0; ks < 2; ks++) {
            bf16x8 af[4];
            #pragma unroll
            for (int m = 0; m < 4; m++) {
                int row = m * 16 + l15;
                int boff = (row * 128 + (ks * 32 + kr0) * 2) ^ ((row & 7) << 4);
                af[m] = *(bf16x8*)(asb + boff);
            }
            #pragma unroll
            for (int m = 0; m < 4; m++)
                #pragma unroll
                for (int nf = 0; nf < 4; nf++)
                    acc[m][nf] = __builtin_amdgcn_mfma_f32_16x16x32_bf16(
                        af[m], bfrag[ks][nf], acc[m][nf], 0, 0, 0);
        }

        int rbase = (lane >> 4) * 4;
        #pragma unroll
        for (int m = 0; m < 4; m++)
            #pragma unroll
            for (int j = 0; j < 4; j++) {
                int o = s_out[m * 16 + rbase + j];
                if (o >= 0)
                    #pragma unroll
                    for (int nf = 0; nf < 4; nf++)
                        atomicAdd(&ybase[(long)o * COUT + nbase + nf * 16 + l15],
                                  acc[m][nf][j]);
            }
        __syncthreads();
    }
}

__global__ __launch_bounds__(256) void convs_atomic_kernel(
    const float* __restrict__ y1,
    const float* __restrict__ Ws,
    const int* __restrict__ in_idx, const int* __restrict__ out_idx,
    const float* __restrict__ ss2,
    float* __restrict__ out)
{
    int k    = blockIdx.y;
    int tid  = threadIdx.x;
    int wave = tid >> 6, lane = tid & 63;

    __shared__ bf16 As[64 * 128];
    __shared__ int  s_out[64];
    __shared__ float s_sc[128], s_sh[128];
    char* asb = (char*)As;

    if (tid < 128) { s_sc[tid] = ss2[tid]; s_sh[tid] = ss2[128 + tid]; }

    const float* Wk = Ws + (long)k * COUT * COUT;
    int nbase = wave * 32;
    int l15 = lane & 15;
    int kr0 = (lane >> 4) * 8;

    bf16x8 bfrag[4][2];
    #pragma unroll
    for (int ks = 0; ks < 4; ks++)
        #pragma unroll
        for (int nf = 0; nf < 2; nf++) {
            const float* p = Wk + (long)(ks * 32 + kr0) * COUT + nbase + nf * 16 + l15;
            bf16x8 b;
            #pragma unroll
            for (int j = 0; j < 8; j++) b[j] = (bf16)p[(long)j * COUT];
            bfrag[ks][nf] = b;
        }

    const int* in_k  = in_idx  + k * R_PAIRS;
    const int* out_k = out_idx + k * R_PAIRS;

    int grow = tid >> 2;
    int gcol = (tid & 3) * 32;

    __syncthreads();

    for (int t = 0; t < OLD_TILES; t++) {
        int pair0 = blockIdx.x * (OLD_TILES * 64) + t * 64;
        {
            int p = pair0 + grow;
            bool valid = p < R_PAIRS;
            long src = valid ? (long)in_k[p] : 0;
            const float4* yr = (const float4*)(y1 + src * COUT + gcol);
            #pragma unroll
            for (int g = 0; g < 4; g++) {
                float4 va = make_float4(0, 0, 0, 0), vb = va;
                if (valid) { va = yr[g * 2]; vb = yr[g * 2 + 1]; }
                float f[8] = {va.x, va.y, va.z, va.w, vb.x, vb.y, vb.z, vb.w};
                bf16x8 h;
                #pragma unroll
                for (int j = 0; j < 8; j++) {
                    int c = gcol + g * 8 + j;
                    h[j] = (bf16)fmaxf(f[j] * s_sc[c] + s_sh[c], 0.f);
                }
                int boff = (grow * 256 + (gcol + g * 8) * 2) ^ ((grow & 7) << 4);
                *(bf16x8*)(asb + boff) = h;
            }
        }
        if (tid < 64) {
            int p = pair0 + tid;
            s_out[tid] = (p < R_PAIRS) ? out_k[p] : -1;
        }
        __syncthreads();

        f32x4 acc[4][2];
        #pragma unroll
        for (int m = 0; m < 4; m++)
            #pragma unroll
            for (int n = 0; n < 2; n++) acc[m][n] = (f32x4)(0.f);

        #pragma unroll
        for (int ks = 0; ks < 4; ks++) {
            bf16x8 af[4];
            #pragma unroll
            for (int m = 0; m < 4; m++) {
                int row = m * 16 + l15;
                int boff = (row * 256 + (ks * 32 + kr0) * 2) ^ ((row & 7) << 4);
                af[m] = *(bf16x8*)(asb + boff);
            }
            #pragma unroll
            for (int m = 0; m < 4; m++)
                #pragma unroll
                for (int nf = 0; nf < 2; nf++)
                    acc[m][nf] = __builtin_amdgcn_mfma_f32_16x16x32_bf16(
                        af[m], bfrag[ks][nf], acc[m][nf], 0, 0, 0);
        }

        int rbase = (lane >> 4) * 4;
        #pragma unroll
        for (int m = 0; m < 4; m++)
            #pragma unroll
            for (int j = 0; j < 4; j++) {
                int o = s_out[m * 16 + rbase + j];
                if (o >= 0)
                    #pragma unroll
                    for (int nf = 0; nf < 2; nf++)
                        atomicAdd(&out[(long)o * COUT + nbase + nf * 16 + l15],
                                  acc[m][nf][j]);
            }
        __syncthreads();
    }
}

// ==================== host ====================
extern "C" void kernel_launch(void* const* d_in, const int* in_sizes, int n_in,
                              void* d_out, int out_size, void* d_ws, size_t ws_size,
                              hipStream_t stream) {
    const float* x       = (const float*)d_in[0];
    const float* gamma1  = (const float*)d_in[1];
    const float* beta1   = (const float*)d_in[2];
    const float* gamma2  = (const float*)d_in[3];
    const float* beta2   = (const float*)d_in[4];
    const float* W1      = (const float*)d_in[5];
    const float* Ws      = (const float*)d_in[6];
    const float* W2      = (const float*)d_in[7];
    const int*   in_idx1   = (const int*)d_in[8];
    const int*   out_idx1  = (const int*)d_in[9];
    const int*   in_idx_s  = (const int*)d_in[10];
    const int*   out_idx_s = (const int*)d_in[11];

    float* out = (float*)d_out;
    char*  ws  = (char*)d_ws;

    auto a256 = [](size_t v) { return (v + 255) & ~(size_t)255; };

    size_t off_y1      = 0;                                    // bf16 y1: 32 MB
    size_t off_x1      = a256(off_y1 + 32000000);              // bf16 x1: 64 MB
    size_t off_y2b     = a256(off_x1 + 64000000);              // bf16 y2b: 32 MB
    size_t off_stats   = a256(off_y2b + 32000000);             // 4 KB (sums1,ss1,ss2)
    size_t off_s2s     = a256(off_stats + 4096);               // 64*256*4 = 64 KB
    size_t off_countO  = a256(off_s2s + 65536);                // 500 KB
    size_t off_cursorO = a256(off_countO + 4 * N_OUT);         // 500 KB
    size_t off_rows    = a256(off_cursorO + 4 * N_OUT);        // 500 KB
    size_t off_bsum    = a256(off_rows + 4 * (N_OUT + 1));     // 1 KB
    size_t off_listF   = a256(off_bsum + 1024);                // 2 MB
    size_t off_wf12    = a256(off_listF + 4 * NPAIRS);         // 256 KB
    size_t off_wfs     = a256(off_wf12 + 262144);              // 256 KB
    size_t need        = off_wfs + 262144;

    if (need > ws_size) {
        // -------- fallback: atomic path (needs only 64 MB + 4 KB) --------
        float* y1f   = (float*)ws;
        float* stats = y1f + (long)N_OUT * COUT;
        float* sums1 = stats;
        float* ss1   = stats + 128;
        float* sums2 = stats + 256;
        float* ss2   = stats + 512;

        hipMemsetAsync(d_out, 0, (size_t)N_OUT * COUT * 4, stream);
        hipMemsetAsync(d_ws,  0, (size_t)N_OUT * COUT * 4 + 768 * 4, stream);

        bn_stats_kernel<64><<<1024, 256, 0, stream>>>(x, N_IN, sums1);
        bn_finalize_kernel<64><<<1, 64, 0, stream>>>(sums1, gamma1, beta1, 1.f / N_IN, ss1);

        dim3 cgrid((R_PAIRS + OLD_TILES * 64 - 1) / (OLD_TILES * 64), K_OFF);
        conv12_atomic_kernel<<<cgrid, 256, 0, stream>>>(x, W1, W2, in_idx1, out_idx1, ss1, y1f, out);

        bn_stats_kernel<128><<<1024, 256, 0, stream>>>(y1f, N_OUT, sums2);
        bn_finalize_kernel<128><<<1, 128, 0, stream>>>(sums2, gamma2, beta2, 1.f / N_OUT, ss2);

        convs_atomic_kernel<<<cgrid, 256, 0, stream>>>(y1f, Ws, in_idx_s, out_idx_s, ss2, out);
        return;
    }

    bf16*  y1      = (bf16*)(ws + off_y1);
    bf16*  x1      = (bf16*)(ws + off_x1);
    bf16*  y2b     = (bf16*)(ws + off_y2b);
    float* sums1   = (float*)(ws + off_stats);    // [256]
    float* ss1     = sums1 + 256;                 // [256]
    float* ss2     = sums1 + 512;                 // [256]
    float* s2s     = (float*)(ws + off_s2s);      // [64][256]
    u32*   countO  = (u32*)(ws + off_countO);
    u32*   cursorO = (u32*)(ws + off_cursorO);
    u32*   rows    = (u32*)(ws + off_rows);
    u32*   bsum    = (u32*)(ws + off_bsum);
    u32*   listF   = (u32*)(ws + off_listF);
    bf16*  wf12    = (bf16*)(ws + off_wf12);
    bf16*  wfs     = (bf16*)(ws + off_wfs);

    int nblk = (N_OUT + 15) / 16;    // 7813

    // ---- BN1 stats + apply -> x1 (bf16); weight prepack ----
    hipMemsetAsync(sums1, 0, 4096, stream);
    hipMemsetAsync(s2s, 0, 65536, stream);
    bn_stats_kernel<64><<<1024, 256, 0, stream>>>(x, N_IN, sums1);
    bn_finalize_kernel<64><<<1, 64, 0, stream>>>(sums1, gamma1, beta1, 1.f / N_IN, ss1);
    bn_apply_f32_kernel<64><<<4096, 256, 0, stream>>>(x, ss1, x1, (long)N_IN * CIN / 8);
    pack12_kernel<<<512, 256, 0, stream>>>(W1, W2, wf12);
    packS_kernel<<<512, 256, 0, stream>>>(Ws, wfs);

    // ---- rulebook 1: out-major sort ----
    hipMemsetAsync(countO, 0, 4 * N_OUT, stream);
    histO_kernel<<<512, 256, 0, stream>>>(out_idx1, countO);
    scan1_kernel<<<NSB_OUT, 256, 0, stream>>>(countO, bsum, N_OUT);
    scan2_kernel<<<1, 256, 0, stream>>>(bsum, rows, NSB_OUT, N_OUT);
    scan3_kernel<<<NSB_OUT, 256, 0, stream>>>(countO, bsum, rows, N_OUT);
    hipMemsetAsync(cursorO, 0, 4 * N_OUT, stream);
    buildF_kernel<<<(NPAIRS + 255) / 256, 256, 0, stream>>>(in_idx1, out_idx1, rows, cursorO, listF);

    // ---- fused conv1+conv2 ----
    fused12_kernel<<<nblk, 256, 0, stream>>>(x1, wf12, rows, listF, y1, y2b, s2s);
    bn_finalize2_kernel<<<1, 128, 0, stream>>>(s2s, gamma2, beta2, ss2);

    // ---- rulebook s ----
    hipMemsetAsync(countO, 0, 4 * N_OUT, stream);
    histO_kernel<<<512, 256, 0, stream>>>(out_idx_s, countO);
    scan1_kernel<<<NSB_OUT, 256, 0, stream>>>(countO, bsum, N_OUT);
    scan2_kernel<<<1, 256, 0, stream>>>(bsum, rows, NSB_OUT, N_OUT);
    scan3_kernel<<<NSB_OUT, 256, 0, stream>>>(countO, bsum, rows, N_OUT);
    hipMemsetAsync(cursorO, 0, 4 * N_OUT, stream);
    buildF_kernel<<<(NPAIRS + 255) / 256, 256, 0, stream>>>(in_idx_s, out_idx_s, rows, cursorO, listF);

    // ---- fused submanifold conv (BN2+ReLU in reduce, +y2b epilogue) ----
    fusedS_kernel<<<nblk, 256, 0, stream>>>(y1, wfs, ss2, rows, listF, y2b, out);
}

// Round 10
// 481.121 us; speedup vs baseline: 1.2804x; 1.2804x over previous
//
#include <hip/hip_runtime.h>

#define K_OFF   8
#define R_PAIRS 62500
#define NPAIRS  500000
#define N_IN    500000
#define N_OUT   125000
#define CIN     64
#define COUT    128
#define BN_EPS  1e-4f
#define SCAN_ELEMS 4096
#define NBINS_KC (N_OUT * K_OFF)     // 1,000,000
#define NSB_KC  245                  // ceil(1e6 / 4096)
#define OLD_TILES 8

typedef __bf16 bf16;
typedef __bf16 bf16x8 __attribute__((ext_vector_type(8)));
typedef float  f32x4  __attribute__((ext_vector_type(4)));
typedef unsigned int u32;

// z swizzle: inject column-group ^ row into bank bits 2-4 (f32-index space).
__device__ __forceinline__ int zoff(int row, int col) {
    int idx = (row << 9) + col;
    return idx ^ ((((col >> 5) ^ row) & 7) << 2);
}

// ==================== BN statistics ====================
template<int C>
__global__ void bn_stats_kernel(const float* __restrict__ x, int n_rows,
                                float* __restrict__ sums /* [2C] */) {
    constexpr int CG = C / 4;
    int tid = blockIdx.x * blockDim.x + threadIdx.x;
    int nth = gridDim.x * blockDim.x;
    const float4* x4 = (const float4*)x;
    long n4 = (long)n_rows * CG;
    int cg = tid % CG;
    float s[4] = {0,0,0,0}, q[4] = {0,0,0,0};
    for (long i = tid; i < n4; i += nth) {
        float4 v = x4[i];
        float f[4] = {v.x, v.y, v.z, v.w};
        #pragma unroll
        for (int j = 0; j < 4; j++) { s[j] += f[j]; q[j] += f[j] * f[j]; }
    }
    __shared__ float acc[2 * C];
    for (int i = threadIdx.x; i < 2 * C; i += blockDim.x) acc[i] = 0.f;
    __syncthreads();
    #pragma unroll
    for (int j = 0; j < 4; j++) {
        atomicAdd(&acc[cg * 4 + j], s[j]);
        atomicAdd(&acc[C + cg * 4 + j], q[j]);
    }
    __syncthreads();
    for (int i = threadIdx.x; i < 2 * C; i += blockDim.x) atomicAdd(&sums[i], acc[i]);
}

template<int C>
__global__ void bn_finalize_kernel(const float* __restrict__ sums,
                                   const float* __restrict__ gamma,
                                   const float* __restrict__ beta,
                                   float inv_n, float* __restrict__ ss) {
    int c = threadIdx.x;
    if (c < C) {
        float m  = sums[c] * inv_n;
        float v  = sums[C + c] * inv_n - m * m;
        float sc = gamma[c] * rsqrtf(v + BN_EPS);
        ss[c]     = sc;
        ss[C + c] = beta[c] - m * sc;
    }
}

// BN2 finalize from 64 striped partial-sum copies
__global__ void bn_finalize2_kernel(const float* __restrict__ S /*[64][256]*/,
                                    const float* __restrict__ gamma,
                                    const float* __restrict__ beta,
                                    float* __restrict__ ss) {
    int c = threadIdx.x;   // 128
    float s = 0.f, q = 0.f;
    for (int st = 0; st < 64; st++) { s += S[st * 256 + c]; q += S[st * 256 + 128 + c]; }
    float m = s / (float)N_OUT;
    float v = q / (float)N_OUT - m * m;
    float sc = gamma[c] * rsqrtf(v + BN_EPS);
    ss[c] = sc; ss[128 + c] = beta[c] - m * sc;
}

// ==================== BN apply + ReLU -> bf16 (fp32 in) ====================
template<int C>
__global__ void bn_apply_f32_kernel(const float* __restrict__ x, const float* __restrict__ ss,
                                    bf16* __restrict__ xo, long items /* rows*C/8 */) {
    constexpr int CG = C / 8;
    long i = (long)blockIdx.x * blockDim.x + threadIdx.x;
    long stride = (long)gridDim.x * blockDim.x;   // multiple of CG
    int cg = (int)(i % CG);
    float sc[8], sh[8];
    #pragma unroll
    for (int j = 0; j < 8; j++) { sc[j] = ss[cg*8+j]; sh[j] = ss[C + cg*8+j]; }
    for (; i < items; i += stride) {
        const float4* p = (const float4*)(x + i * 8);
        float4 a = p[0], b = p[1];
        float f[8] = {a.x,a.y,a.z,a.w,b.x,b.y,b.z,b.w};
        bf16x8 h;
        #pragma unroll
        for (int j = 0; j < 8; j++) h[j] = (bf16)fmaxf(f[j]*sc[j] + sh[j], 0.f);
        *(bf16x8*)(xo + i * 8) = h;
    }
}

// ==================== weight prepack (fragment order) ====================
__global__ void pack12_kernel(const float* __restrict__ W1, const float* __restrict__ W2,
                              bf16* __restrict__ Wf) {
    int idx = blockIdx.x * 256 + threadIdx.x;      // 131072
    int j = idx & 7;
    int lane = (idx >> 3) & 63;
    int fi = idx >> 9;            // 0..255
    int ks = fi >> 4, nfrag = fi & 15;
    int k512 = ks * 32 + (lane >> 4) * 8 + j;
    int koff = k512 >> 6, kc = k512 & 63;
    int c = nfrag * 16 + (lane & 15);
    const float* W = (c < 128) ? W1 : W2;
    Wf[idx] = (bf16)W[((long)koff * CIN + kc) * COUT + (c & 127)];
}

__global__ void packS_kernel(const float* __restrict__ Ws, bf16* __restrict__ Wf) {
    int idx = blockIdx.x * 256 + threadIdx.x;      // 131072
    int j = idx & 7;
    int lane = (idx >> 3) & 63;
    int fi = idx >> 9;            // 0..255
    int ksg = fi >> 3, nfrag = fi & 7;
    int k1024 = ksg * 32 + (lane >> 4) * 8 + j;
    int koff = k1024 >> 7, kc = k1024 & 127;
    int c = nfrag * 16 + (lane & 15);
    Wf[idx] = (bf16)Ws[((long)koff * COUT + kc) * COUT + c];
}

// ==================== hist over (out,k) bins ====================
__global__ void histOK_kernel(const int* __restrict__ oidx, u32* __restrict__ counts) {
    int p = blockIdx.x * blockDim.x + threadIdx.x;
    int stride = gridDim.x * blockDim.x;
    for (; p < NPAIRS; p += stride) {
        int bin = oidx[p] * K_OFF + p / R_PAIRS;
        atomicAdd(&counts[bin], 1u);
    }
}

// ==================== 3-level scan (n up to 1M) ====================
__global__ void scan1_kernel(const u32* __restrict__ counts, u32* __restrict__ bsum, int n) {
    __shared__ u32 sd[256];
    int tid = threadIdx.x;
    int base = blockIdx.x * SCAN_ELEMS + tid * 16;
    u32 s = 0;
    #pragma unroll
    for (int j = 0; j < 16; j++) { int i = base + j; if (i < n) s += counts[i]; }
    sd[tid] = s; __syncthreads();
    for (int st = 128; st > 0; st >>= 1) { if (tid < st) sd[tid] += sd[tid + st]; __syncthreads(); }
    if (tid == 0) bsum[blockIdx.x] = sd[0];
}

__global__ void scan2_kernel(u32* __restrict__ bsum, u32* __restrict__ starts, int nb, int n) {
    __shared__ u32 sd[256];
    int tid = threadIdx.x;
    u32 v = (tid < nb) ? bsum[tid] : 0;
    sd[tid] = v; __syncthreads();
    for (int st = 1; st < 256; st <<= 1) {
        u32 t = (tid >= st) ? sd[tid - st] : 0;
        __syncthreads();
        sd[tid] += t;
        __syncthreads();
    }
    if (tid < nb) bsum[tid] = sd[tid] - v;     // exclusive
    if (tid == 255) starts[n] = sd[255];       // total
}

__global__ void scan3_kernel(const u32* __restrict__ counts, const u32* __restrict__ bsum,
                             u32* __restrict__ starts, int n) {
    __shared__ u32 sd[256];
    int tid = threadIdx.x;
    int base = blockIdx.x * SCAN_ELEMS + tid * 16;
    u32 v[16]; u32 s = 0;
    #pragma unroll
    for (int j = 0; j < 16; j++) { int i = base + j; v[j] = (i < n) ? counts[i] : 0; s += v[j]; }
    sd[tid] = s; __syncthreads();
    for (int st = 1; st < 256; st <<= 1) {
        u32 t = (tid >= st) ? sd[tid - st] : 0;
        __syncthreads();
        sd[tid] += t;
        __syncthreads();
    }
    u32 run = bsum[blockIdx.x] + sd[tid] - s;
    #pragma unroll
    for (int j = 0; j < 16; j++) { int i = base + j; if (i < n) starts[i] = run; run += v[j]; }
}

// ==================== build (out,k)-sorted gather list ====================
__global__ void buildF_kernel(const int* __restrict__ iidx, const int* __restrict__ oidx,
                              const u32* __restrict__ kstart, u32* __restrict__ cursor,
                              u32* __restrict__ listF) {
    int p = blockIdx.x * 256 + threadIdx.x;
    if (p >= NPAIRS) return;
    int bin = oidx[p] * K_OFF + p / R_PAIRS;
    u32 pos = kstart[bin] + atomicAdd(&cursor[bin], 1u);
    listF[pos] = (u32)iidx[p];
}

// ==================== fused conv1+conv2: segment-owner z-build ====================
// block: 16 out rows. Thread (row=tid>>4, sl=tid&15) owns k=sl>>1, ch 32-slice (sl&1):
// walks its own (out,k) segment of listF, gathers x1 slices, accumulates in regs.
// z [16][512] fp32 via zoff. GEMM waves: wave w -> cat cols w*64..+64.
__global__ __launch_bounds__(256) void fused12_kernel(
    const bf16* __restrict__ x1, const bf16* __restrict__ Wf,
    const u32* __restrict__ kstart, const u32* __restrict__ listF,
    bf16* __restrict__ y1, bf16* __restrict__ y2b, float* __restrict__ sums2s)
{
    __shared__ float z[16 * 512];     // 32 KB
    int tid = threadIdx.x, lane = tid & 63, wave = tid >> 6;
    int o0 = blockIdx.x * 16;
    int nrow = min(16, N_OUT - o0);

    int myrow = tid >> 4, sl = tid & 15;
    int kown = sl >> 1, ch0 = (sl & 1) * 32;

    // ---- segment-owner gather+reduce ----
    f32x4 a[8];
    #pragma unroll
    for (int g = 0; g < 8; g++) a[g] = (f32x4)(0.f);
    if (myrow < nrow) {
        long bin = (long)(o0 + myrow) * K_OFF + kown;
        u32 s = kstart[bin], e = kstart[bin + 1];
        for (u32 p = s; p < e; p++) {
            int in = (int)listF[p];
            const int4* src = (const int4*)(x1 + (size_t)in * 64 + ch0);
            #pragma unroll
            for (int q = 0; q < 4; q++) {
                int4 vi = src[q];
                bf16x8 hv = *(bf16x8*)&vi;
                #pragma unroll
                for (int j = 0; j < 8; j++)
                    a[q * 2 + (j >> 2)][j & 3] += (float)hv[j];
            }
        }
    }
    // z write (full coverage by owners; stale rows >= nrow never read downstream of GEMM mask,
    // but zero them anyway for safety of BN stage reads)
    {
        int colb = kown * 64 + ch0;
        #pragma unroll
        for (int g = 0; g < 8; g++)
            *(f32x4*)&z[zoff(myrow, colb + g * 4)] = a[g];
    }
    __syncthreads();

    // ---- GEMM: [16 x 512] x [512 x 256] ----
    int l15 = lane & 15, kr0 = (lane >> 4) * 8;
    f32x4 acc[4];
    #pragma unroll
    for (int nf = 0; nf < 4; nf++) acc[nf] = (f32x4)(0.f);
    for (int ks = 0; ks < 16; ks++) {
        int colb = ks * 32 + kr0;
        f32x4 a0 = *(f32x4*)&z[zoff(l15, colb)];
        f32x4 a1 = *(f32x4*)&z[zoff(l15, colb + 4)];
        bf16x8 af;
        #pragma unroll
        for (int j = 0; j < 4; j++) { af[j] = (bf16)a0[j]; af[4 + j] = (bf16)a1[j]; }
        #pragma unroll
        for (int nf = 0; nf < 4; nf++) {
            bf16x8 bf = *(const bf16x8*)(Wf + ((size_t)(ks * 16 + wave * 4 + nf) * 64 + lane) * 8);
            acc[nf] = __builtin_amdgcn_mfma_f32_16x16x32_bf16(af, bf, acc[nf], 0, 0, 0);
        }
    }
    __syncthreads();   // all z reads done -> reuse as stage

    // stage bf16 [16 rows][256 cat cols]
    bf16* st = (bf16*)z;
    int rb = (lane >> 4) * 4;
    #pragma unroll
    for (int nf = 0; nf < 4; nf++)
        #pragma unroll
        for (int j = 0; j < 4; j++)
            st[(rb + j) * 256 + wave * 64 + nf * 16 + l15] = (bf16)acc[nf][j];
    __syncthreads();

    // BN2 stats over y1 cols (0..127), striped atomics
    if (tid < 128) {
        float s = 0.f, q = 0.f;
        for (int r = 0; r < nrow; r++) { float v = (float)st[r * 256 + tid]; s += v; q += v * v; }
        int sb = (blockIdx.x & 63) * 256;
        atomicAdd(&sums2s[sb + tid], s);
        atomicAdd(&sums2s[sb + 128 + tid], q);
    }
    // output: thread -> (row, 32B segment)
    {
        int row = tid >> 4, seg = tid & 15;
        if (row < nrow) {
            const int4* src = (const int4*)(st + row * 256 + seg * 16);
            int4 v0 = src[0], v1 = src[1];
            bf16* dst = (seg < 8) ? (y1  + (size_t)(o0 + row) * 128 + seg * 16)
                                  : (y2b + (size_t)(o0 + row) * 128 + (seg - 8) * 16);
            ((int4*)dst)[0] = v0; ((int4*)dst)[1] = v1;
        }
    }
}

// ==================== fused submanifold conv: segment-owner z-build ================
// Thread (row, sl): ch slice (sl&3)*32, two segments k=sl>>2 (aA) and k=4+(sl>>2) (aB).
// BN2+ReLU applied in the fp32 reduce. Two K=512 GEMM halves share z.
__global__ __launch_bounds__(256) void fusedS_kernel(
    const bf16* __restrict__ y1, const bf16* __restrict__ Wf, const float* __restrict__ ss2,
    const u32* __restrict__ kstart, const u32* __restrict__ listF,
    const bf16* __restrict__ y2b, float* __restrict__ out)
{
    __shared__ float z[16 * 512];     // 32 KB
    __shared__ float s_sc[128], s_sh[128];
    int tid = threadIdx.x, lane = tid & 63, wave = tid >> 6;
    if (tid < 128) { s_sc[tid] = ss2[tid]; s_sh[tid] = ss2[128 + tid]; }
    int o0 = blockIdx.x * 16;
    int nrow = min(16, N_OUT - o0);

    int myrow = tid >> 4, sl = tid & 15;
    int kq = sl >> 2, ch0 = (sl & 3) * 32;

    __syncthreads();   // s_sc/s_sh ready

    f32x4 aA[8], aB[8];
    #pragma unroll
    for (int g = 0; g < 8; g++) { aA[g] = (f32x4)(0.f); aB[g] = (f32x4)(0.f); }

    if (myrow < nrow) {
        long binbase = (long)(o0 + myrow) * K_OFF;
        #pragma unroll
        for (int h = 0; h < 2; h++) {
            long bin = binbase + h * 4 + kq;
            u32 s = kstart[bin], e = kstart[bin + 1];
            for (u32 p = s; p < e; p++) {
                int in = (int)listF[p];
                const int4* src = (const int4*)(y1 + (size_t)in * 128 + ch0);
                #pragma unroll
                for (int q = 0; q < 4; q++) {
                    int4 vi = src[q];
                    bf16x8 hv = *(bf16x8*)&vi;
                    #pragma unroll
                    for (int j = 0; j < 8; j++) {
                        int c = ch0 + q * 8 + j;
                        float v = fmaxf((float)hv[j] * s_sc[c] + s_sh[c], 0.f);
                        if (h == 0) aA[q * 2 + (j >> 2)][j & 3] += v;
                        else        aB[q * 2 + (j >> 2)][j & 3] += v;
                    }
                }
            }
        }
    }

    int l15 = lane & 15, kr0 = (lane >> 4) * 8;
    f32x4 acc[2];
    acc[0] = (f32x4)(0.f); acc[1] = (f32x4)(0.f);
    int colw = kq * 128 + ch0;

    #pragma unroll
    for (int h = 0; h < 2; h++) {
        if (h) __syncthreads();   // GEMM h=0 z reads done
        if (h == 0) {
            #pragma unroll
            for (int g = 0; g < 8; g++) *(f32x4*)&z[zoff(myrow, colw + g * 4)] = aA[g];
        } else {
            #pragma unroll
            for (int g = 0; g < 8; g++) *(f32x4*)&z[zoff(myrow, colw + g * 4)] = aB[g];
        }
        __syncthreads();

        for (int ks = 0; ks < 16; ks++) {
            int colb = ks * 32 + kr0;
            f32x4 a0 = *(f32x4*)&z[zoff(l15, colb)];
            f32x4 a1 = *(f32x4*)&z[zoff(l15, colb + 4)];
            bf16x8 af;
            #pragma unroll
            for (int j = 0; j < 4; j++) { af[j] = (bf16)a0[j]; af[4 + j] = (bf16)a1[j]; }
            #pragma unroll
            for (int nf = 0; nf < 2; nf++) {
                int fi = (h * 16 + ks) * 8 + wave * 2 + nf;
                bf16x8 bf = *(const bf16x8*)(Wf + ((size_t)fi * 64 + lane) * 8);
                acc[nf] = __builtin_amdgcn_mfma_f32_16x16x32_bf16(af, bf, acc[nf], 0, 0, 0);
            }
        }
    }
    __syncthreads();

    // stage fp32 [16][128]
    int rb = (lane >> 4) * 4;
    #pragma unroll
    for (int nf = 0; nf < 2; nf++)
        #pragma unroll
        for (int j = 0; j < 4; j++)
            z[(rb + j) * 128 + wave * 32 + nf * 16 + l15] = acc[nf][j];
    __syncthreads();

    {
        int orow = tid >> 4, seg = tid & 15;   // 8 floats each
        if (orow < nrow) {
            f32x4 s0 = *(f32x4*)&z[orow * 128 + seg * 8];
            f32x4 s1 = *(f32x4*)&z[orow * 128 + seg * 8 + 4];
            int4 yv = *(const int4*)(y2b + (size_t)(o0 + orow) * 128 + seg * 8);
            bf16x8 hy = *(bf16x8*)&yv;
            float4 w0 = make_float4(s0[0] + (float)hy[0], s0[1] + (float)hy[1],
                                    s0[2] + (float)hy[2], s0[3] + (float)hy[3]);
            float4 w1 = make_float4(s1[0] + (float)hy[4], s1[1] + (float)hy[5],
                                    s1[2] + (float)hy[6], s1[3] + (float)hy[7]);
            float* dst = out + (size_t)(o0 + orow) * 128 + seg * 8;
            *(float4*)dst = w0;
            *(float4*)(dst + 4) = w1;
        }
    }
}

// ==================== fallback (round-1 atomic path) ====================
__global__ __launch_bounds__(256) void conv12_atomic_kernel(
    const float* __restrict__ x,
    const float* __restrict__ W1, const float* __restrict__ W2,
    const int* __restrict__ in_idx, const int* __restrict__ out_idx,
    const float* __restrict__ ss1,
    float* __restrict__ y1, float* __restrict__ y2)
{
    int k    = blockIdx.y;
    int tid  = threadIdx.x;
    int wave = tid >> 6, lane = tid & 63;

    __shared__ bf16 As[64 * 64];
    __shared__ int  s_out[64];
    __shared__ float s_sc[64], s_sh[64];
    char* asb = (char*)As;

    if (tid < 64) { s_sc[tid] = ss1[tid]; s_sh[tid] = ss1[64 + tid]; }

    const float* Wk = ((wave & 2) ? W2 : W1) + (long)k * CIN * COUT;
    int nbase = (wave & 1) * 64;
    int l15 = lane & 15;
    int kr0 = (lane >> 4) * 8;

    bf16x8 bfrag[2][4];
    #pragma unroll
    for (int ks = 0; ks < 2; ks++)
        #pragma unroll
        for (int nf = 0; nf < 4; nf++) {
            const float* p = Wk + (long)(ks * 32 + kr0) * COUT + nbase + nf * 16 + l15;
            bf16x8 b;
            #pragma unroll
            for (int j = 0; j < 8; j++) b[j] = (bf16)p[(long)j * COUT];
            bfrag[ks][nf] = b;
        }

    const int* in_k  = in_idx  + k * R_PAIRS;
    const int* out_k = out_idx + k * R_PAIRS;
    float* ybase = (wave & 2) ? y2 : y1;

    int grow = tid >> 2;
    int gcol = (tid & 3) * 16;

    __syncthreads();

    for (int t = 0; t < OLD_TILES; t++) {
        int pair0 = blockIdx.x * (OLD_TILES * 64) + t * 64;
        {
            int p = pair0 + grow;
            bool valid = p < R_PAIRS;
            long src = valid ? (long)in_k[p] : 0;
            const float4* xr = (const float4*)(x + src * CIN + gcol);
            #pragma unroll
            for (int g = 0; g < 2; g++) {
                float4 va = make_float4(0, 0, 0, 0), vb = va;
                if (valid) { va = xr[g * 2]; vb = xr[g * 2 + 1]; }
                float f[8] = {va.x, va.y, va.z, va.w, vb.x, vb.y, vb.z, vb.w};
                bf16x8 h;
                #pragma unroll
                for (int j = 0; j < 8; j++) {
                    int c = gcol + g * 8 + j;
                    h[j] = (bf16)fmaxf(f[j] * s_sc[c] + s_sh[c], 0.f);
                }
                int boff = ((grow * 128) + (gcol + g * 8) * 2) ^ ((grow & 7) << 4);
                *(bf16x8*)(asb + boff) = h;
            }
        }
        if (tid < 64) {
            int p = pair0 + tid;
            s_out[tid] = (p < R_PAIRS) ? out_k[p] : -1;
        }
        __syncthreads();

        f32x4 acc[4][4];
        #pragma unroll
        for (int m = 0; m < 4; m++)
            #pragma unroll
            for (int n = 0; n < 4; n++) acc[m][n] = (f32x4)(0.f);

        #pragma unroll
        for (int ks = 0; ks < 2; ks++) {
            bf16x8 af[4];
            #pragma unroll
            for (int m = 0; m < 4; m++) {
                int row = m * 16 + l15;
                int boff = (row * 128 + (ks * 32 + kr0) * 2) ^ ((row & 7) << 4);
                af[m] = *(bf16x8*)(asb + boff);
            }
            #pragma unroll
            for (int m = 0; m < 4; m++)
                #pragma unroll
                for (int nf = 0; nf < 4; nf++)
                    acc[m][nf] = __builtin_amdgcn_mfma_f32_16x16x32_bf16(
                        af[m], bfrag[ks][nf], acc[m][nf], 0, 0, 0);
        }

        int rbase = (lane >> 4) * 4;
        #pragma unroll
        for (int m = 0; m < 4; m++)
            #pragma unroll
            for (int j = 0; j < 4; j++) {
                int o = s_out[m * 16 + rbase + j];
                if (o >= 0)
                    #pragma unroll
                    for (int nf = 0; nf < 4; nf++)
                        atomicAdd(&ybase[(long)o * COUT + nbase + nf * 16 + l15],
                                  acc[m][nf][j]);
            }
        __syncthreads();
    }
}

__global__ __launch_bounds__(256) void convs_atomic_kernel(
    const float* __restrict__ y1,
    const float* __restrict__ Ws,
    const int* __restrict__ in_idx, const int* __restrict__ out_idx,
    const float* __restrict__ ss2,
    float* __restrict__ out)
{
    int k    = blockIdx.y;
    int tid  = threadIdx.x;
    int wave = tid >> 6, lane = tid & 63;

    __shared__ bf16 As[64 * 128];
    __shared__ int  s_out[64];
    __shared__ float s_sc[128], s_sh[128];
    char* asb = (char*)As;

    if (tid < 128) { s_sc[tid] = ss2[tid]; s_sh[tid] = ss2[128 + tid]; }

    const float* Wk = Ws + (long)k * COUT * COUT;
    int nbase = wave * 32;
    int l15 = lane & 15;
    int kr0 = (lane >> 4) * 8;

    bf16x8 bfrag[4][2];
    #pragma unroll
    for (int ks = 0; ks < 4; ks++)
        #pragma unroll
        for (int nf = 0; nf < 2; nf++) {
            const float* p = Wk + (long)(ks * 32 + kr0) * COUT + nbase + nf * 16 + l15;
            bf16x8 b;
            #pragma unroll
            for (int j = 0; j < 8; j++) b[j] = (bf16)p[(long)j * COUT];
            bfrag[ks][nf] = b;
        }

    const int* in_k  = in_idx  + k * R_PAIRS;
    const int* out_k = out_idx + k * R_PAIRS;

    int grow = tid >> 2;
    int gcol = (tid & 3) * 32;

    __syncthreads();

    for (int t = 0; t < OLD_TILES; t++) {
        int pair0 = blockIdx.x * (OLD_TILES * 64) + t * 64;
        {
            int p = pair0 + grow;
            bool valid = p < R_PAIRS;
            long src = valid ? (long)in_k[p] : 0;
            const float4* yr = (const float4*)(y1 + src * COUT + gcol);
            #pragma unroll
            for (int g = 0; g < 4; g++) {
                float4 va = make_float4(0, 0, 0, 0), vb = va;
                if (valid) { va = yr[g * 2]; vb = yr[g * 2 + 1]; }
                float f[8] = {va.x, va.y, va.z, va.w, vb.x, vb.y, vb.z, vb.w};
                bf16x8 h;
                #pragma unroll
                for (int j = 0; j < 8; j++) {
                    int c = gcol + g * 8 + j;
                    h[j] = (bf16)fmaxf(f[j] * s_sc[c] + s_sh[c], 0.f);
                }
                int boff = (grow * 256 + (gcol + g * 8) * 2) ^ ((grow & 7) << 4);
                *(bf16x8*)(asb + boff) = h;
            }
        }
        if (tid < 64) {
            int p = pair0 + tid;
            s_out[tid] = (p < R_PAIRS) ? out_k[p] : -1;
        }
        __syncthreads();

        f32x4 acc[4][2];
        #pragma unroll
        for (int m = 0; m < 4; m++)
            #pragma unroll
            for (int n = 0; n < 2; n++) acc[m][n] = (f32x4)(0.f);

        #pragma unroll
        for (int ks = 0; ks < 4; ks++) {
            bf16x8 af[4];
            #pragma unroll
            for (int m = 0; m < 4; m++) {
                int row = m * 16 + l15;
                int boff = (row * 256 + (ks * 32 + kr0) * 2) ^ ((row & 7) << 4);
                af[m] = *(bf16x8*)(asb + boff);
            }
            #pragma unroll
            for (int m = 0; m < 4; m++)
                #pragma unroll
                for (int nf = 0; nf < 2; nf++)
                    acc[m][nf] = __builtin_amdgcn_mfma_f32_16x16x32_bf16(
                        af[m], bfrag[ks][nf], acc[m][nf], 0, 0, 0);
        }

        int rbase = (lane >> 4) * 4;
        #pragma unroll
        for (int m = 0; m < 4; m++)
            #pragma unroll
            for (int j = 0; j < 4; j++) {
                int o = s_out[m * 16 + rbase + j];
                if (o >= 0)
                    #pragma unroll
                    for (int nf = 0; nf < 2; nf++)
                        atomicAdd(&out[(long)o * COUT + nbase + nf * 16 + l15],
                                  acc[m][nf][j]);
            }
        __syncthreads();
    }
}

// ==================== host ====================
extern "C" void kernel_launch(void* const* d_in, const int* in_sizes, int n_in,
                              void* d_out, int out_size, void* d_ws, size_t ws_size,
                              hipStream_t stream) {
    const float* x       = (const float*)d_in[0];
    const float* gamma1  = (const float*)d_in[1];
    const float* beta1   = (const float*)d_in[2];
    const float* gamma2  = (const float*)d_in[3];
    const float* beta2   = (const float*)d_in[4];
    const float* W1      = (const float*)d_in[5];
    const float* Ws      = (const float*)d_in[6];
    const float* W2      = (const float*)d_in[7];
    const int*   in_idx1   = (const int*)d_in[8];
    const int*   out_idx1  = (const int*)d_in[9];
    const int*   in_idx_s  = (const int*)d_in[10];
    const int*   out_idx_s = (const int*)d_in[11];

    float* out = (float*)d_out;
    char*  ws  = (char*)d_ws;

    auto a256 = [](size_t v) { return (v + 255) & ~(size_t)255; };

    size_t off_y1      = 0;                                    // bf16 y1: 32 MB
    size_t off_x1      = a256(off_y1 + 32000000);              // bf16 x1: 64 MB
    size_t off_y2b     = a256(off_x1 + 64000000);              // bf16 y2b: 32 MB
    size_t off_stats   = a256(off_y2b + 32000000);             // 4 KB (sums1,ss1,ss2)
    size_t off_s2s     = a256(off_stats + 4096);               // 64*256*4 = 64 KB
    size_t off_counts  = a256(off_s2s + 65536);                // 4 MB (hist/cursor)
    size_t off_kstart  = a256(off_counts + 4ull * NBINS_KC);   // 4 MB + 4
    size_t off_bsum    = a256(off_kstart + 4ull * (NBINS_KC + 1));  // 1 KB
    size_t off_listF   = a256(off_bsum + 1024);                // 2 MB
    size_t off_wf12    = a256(off_listF + 4 * NPAIRS);         // 256 KB
    size_t off_wfs     = a256(off_wf12 + 262144);              // 256 KB
    size_t need        = off_wfs + 262144;

    if (need > ws_size) {
        // -------- fallback: atomic path (needs only 64 MB + 4 KB) --------
        float* y1f   = (float*)ws;
        float* stats = y1f + (long)N_OUT * COUT;
        float* sums1 = stats;
        float* ss1   = stats + 128;
        float* sums2 = stats + 256;
        float* ss2   = stats + 512;

        hipMemsetAsync(d_out, 0, (size_t)N_OUT * COUT * 4, stream);
        hipMemsetAsync(d_ws,  0, (size_t)N_OUT * COUT * 4 + 768 * 4, stream);

        bn_stats_kernel<64><<<1024, 256, 0, stream>>>(x, N_IN, sums1);
        bn_finalize_kernel<64><<<1, 64, 0, stream>>>(sums1, gamma1, beta1, 1.f / N_IN, ss1);

        dim3 cgrid((R_PAIRS + OLD_TILES * 64 - 1) / (OLD_TILES * 64), K_OFF);
        conv12_atomic_kernel<<<cgrid, 256, 0, stream>>>(x, W1, W2, in_idx1, out_idx1, ss1, y1f, out);

        bn_stats_kernel<128><<<1024, 256, 0, stream>>>(y1f, N_OUT, sums2);
        bn_finalize_kernel<128><<<1, 128, 0, stream>>>(sums2, gamma2, beta2, 1.f / N_OUT, ss2);

        convs_atomic_kernel<<<cgrid, 256, 0, stream>>>(y1f, Ws, in_idx_s, out_idx_s, ss2, out);
        return;
    }

    bf16*  y1      = (bf16*)(ws + off_y1);
    bf16*  x1      = (bf16*)(ws + off_x1);
    bf16*  y2b     = (bf16*)(ws + off_y2b);
    float* sums1   = (float*)(ws + off_stats);    // [256]
    float* ss1     = sums1 + 256;                 // [256]
    float* ss2     = sums1 + 512;                 // [256]
    float* s2s     = (float*)(ws + off_s2s);      // [64][256]
    u32*   counts  = (u32*)(ws + off_counts);
    u32*   kstart  = (u32*)(ws + off_kstart);
    u32*   bsum    = (u32*)(ws + off_bsum);
    u32*   listF   = (u32*)(ws + off_listF);
    bf16*  wf12    = (bf16*)(ws + off_wf12);
    bf16*  wfs     = (bf16*)(ws + off_wfs);

    int nblk = (N_OUT + 15) / 16;    // 7813

    // ---- BN1 stats + apply -> x1 (bf16); weight prepack ----
    hipMemsetAsync(sums1, 0, 4096, stream);
    hipMemsetAsync(s2s, 0, 65536, stream);
    bn_stats_kernel<64><<<1024, 256, 0, stream>>>(x, N_IN, sums1);
    bn_finalize_kernel<64><<<1, 64, 0, stream>>>(sums1, gamma1, beta1, 1.f / N_IN, ss1);
    bn_apply_f32_kernel<64><<<4096, 256, 0, stream>>>(x, ss1, x1, (long)N_IN * CIN / 8);
    pack12_kernel<<<512, 256, 0, stream>>>(W1, W2, wf12);
    packS_kernel<<<512, 256, 0, stream>>>(Ws, wfs);

    // ---- rulebook 1: (out,k)-sorted list ----
    hipMemsetAsync(counts, 0, 4ull * NBINS_KC, stream);
    histOK_kernel<<<512, 256, 0, stream>>>(out_idx1, counts);
    scan1_kernel<<<NSB_KC, 256, 0, stream>>>(counts, bsum, NBINS_KC);
    scan2_kernel<<<1, 256, 0, stream>>>(bsum, kstart, NSB_KC, NBINS_KC);
    scan3_kernel<<<NSB_KC, 256, 0, stream>>>(counts, bsum, kstart, NBINS_KC);
    hipMemsetAsync(counts, 0, 4ull * NBINS_KC, stream);
    buildF_kernel<<<(NPAIRS + 255) / 256, 256, 0, stream>>>(in_idx1, out_idx1, kstart, counts, listF);

    // ---- fused conv1+conv2 ----
    fused12_kernel<<<nblk, 256, 0, stream>>>(x1, wf12, kstart, listF, y1, y2b, s2s);
    bn_finalize2_kernel<<<1, 128, 0, stream>>>(s2s, gamma2, beta2, ss2);

    // ---- rulebook s ----
    hipMemsetAsync(counts, 0, 4ull * NBINS_KC, stream);
    histOK_kernel<<<512, 256, 0, stream>>>(out_idx_s, counts);
    scan1_kernel<<<NSB_KC, 256, 0, stream>>>(counts, bsum, NBINS_KC);
    scan2_kernel<<<1, 256, 0, stream>>>(bsum, kstart, NSB_KC, NBINS_KC);
    scan3_kernel<<<NSB_KC, 256, 0, stream>>>(counts, bsum, kstart, NBINS_KC);
    hipMemsetAsync(counts, 0, 4ull * NBINS_KC, stream);
    buildF_kernel<<<(NPAIRS + 255) / 256, 256, 0, stream>>>(in_idx_s, out_idx_s, kstart, counts, listF);

    // ---- fused submanifold conv (BN2+ReLU in reduce, +y2b epilogue) ----
    fusedS_kernel<<<nblk, 256, 0, stream>>>(y1, wfs, ss2, kstart, listF, y2b, out);
}